// Round 5
// baseline (1296.185 us; speedup 1.0000x reference)
//
#include <hip/hip_runtime.h>

#define IN_C 256
#define HID_C 256
#define OUT_C 128
#define NUM_GRAPHS 64

typedef _Float16 half4v __attribute__((ext_vector_type(4)));
typedef _Float16 half8v __attribute__((ext_vector_type(8)));
typedef float f32x4 __attribute__((ext_vector_type(4)));

// ---------------- degree / CSR build ----------------

__global__ __launch_bounds__(256) void count_deg_kernel(const int* __restrict__ dst, int E,
                                                        int* __restrict__ cnt) {
    int e = blockIdx.x * 256 + threadIdx.x;
    if (e < E) atomicAdd(&cnt[dst[e]], 1);
}

__global__ __launch_bounds__(256) void dinv_kernel(const int* __restrict__ cnt,
                                                   float* __restrict__ dinv, int N) {
    int i = blockIdx.x * 256 + threadIdx.x;
    if (i < N) dinv[i] = rsqrtf((float)(cnt[i] + 1));  // +1 self loop
}

__global__ __launch_bounds__(1024) void scan_kernel(const int* __restrict__ cnt,
                                                    int* __restrict__ rowptr, int N) {
    __shared__ int sums[1024];
    int tid = threadIdx.x;
    int chunk = (N + 1023) >> 10;
    int start = tid * chunk;
    int end = min(start + chunk, N);
    int s = 0;
    for (int i = start; i < end; ++i) s += cnt[i];
    sums[tid] = s;
    __syncthreads();
    for (int off = 1; off < 1024; off <<= 1) {
        int t = (tid >= off) ? sums[tid - off] : 0;
        __syncthreads();
        sums[tid] += t;
        __syncthreads();
    }
    int run = (tid == 0) ? 0 : sums[tid - 1];
    for (int i = start; i < end; ++i) { rowptr[i] = run; run += cnt[i]; }
    if (tid == 1023) rowptr[N] = sums[1023];
}

__global__ __launch_bounds__(256) void scatter_kernel(const int* __restrict__ src,
                                                      const int* __restrict__ dst, int E,
                                                      const int* __restrict__ rowptr,
                                                      int* __restrict__ fill,
                                                      int* __restrict__ csr) {
    int e = blockIdx.x * 256 + threadIdx.x;
    if (e < E) {
        int d = dst[e];
        int pos = rowptr[d] + atomicAdd(&fill[d], 1);
        csr[pos] = src[e];
    }
}

// ---------------- dtype prep ----------------

// W [K][C] f32  ->  Wt [C][K] f16
__global__ __launch_bounds__(256) void wt_f16_kernel(const float* __restrict__ W,
                                                     _Float16* __restrict__ Wt, int K, int C) {
    int idx = blockIdx.x * 256 + threadIdx.x;
    if (idx < K * C) {
        int k = idx / C, c = idx - k * C;
        Wt[c * K + k] = (_Float16)W[idx];
    }
}

// ---------------- MFMA f16 GEMM with fused dinv row-scale ----------------
// InT = _Float16 or float (converted during LDS staging).

template <int BN, typename InT>
__global__ __launch_bounds__(256) void gemm_f16_kernel(const InT* __restrict__ A,
                                                       const _Float16* __restrict__ Bt,
                                                       const float* __restrict__ dinv,
                                                       _Float16* __restrict__ HS,
                                                       int nRows) {
    constexpr int K = 256;
    constexpr int BK = 32;
    constexpr int LDR = 40;
    constexpr int NF = BN / 64;

    __shared__ __align__(16) _Float16 Al[64 * LDR];
    __shared__ __align__(16) _Float16 Bl[BN * LDR];

    const int tid = threadIdx.x;
    const int wave = tid >> 6;
    const int lane = tid & 63;
    const int row0 = blockIdx.x << 6;

    const int ar = tid >> 2;
    const int ac = (tid & 3) << 3;
    const int arow = min(row0 + ar, nRows - 1);

    const int fr = lane & 15;
    const int k8 = lane >> 4;

    f32x4 acc[4][NF] = {};

    for (int k0 = 0; k0 < K; k0 += BK) {
        half8v av;
        if constexpr (sizeof(InT) == 2) {
            av = *(const half8v*)((const _Float16*)A + (size_t)arow * K + k0 + ac);
        } else {
            const float* ap = (const float*)A + (size_t)arow * K + k0 + ac;
            f32x4 lo = *(const f32x4*)(ap);
            f32x4 hi = *(const f32x4*)(ap + 4);
            half4v l = __builtin_convertvector(lo, half4v);
            half4v h = __builtin_convertvector(hi, half4v);
            av = __builtin_shufflevector(l, h, 0, 1, 2, 3, 4, 5, 6, 7);
        }
        half8v bv[NF];
#pragma unroll
        for (int j = 0; j < NF; ++j)
            bv[j] = *(const half8v*)(Bt + (size_t)(ar + 64 * j) * K + k0 + ac);
        __syncthreads();
        *(half8v*)(Al + ar * LDR + ac) = av;
#pragma unroll
        for (int j = 0; j < NF; ++j)
            *(half8v*)(Bl + (ar + 64 * j) * LDR + ac) = bv[j];
        __syncthreads();

        half8v af[4], bf[NF];
#pragma unroll
        for (int m = 0; m < 4; ++m)
            af[m] = *(const half8v*)(Al + (m * 16 + fr) * LDR + k8 * 8);
#pragma unroll
        for (int n = 0; n < NF; ++n)
            bf[n] = *(const half8v*)(Bl + (wave * (BN / 4) + n * 16 + fr) * LDR + k8 * 8);
#pragma unroll
        for (int m = 0; m < 4; ++m)
#pragma unroll
            for (int n = 0; n < NF; ++n)
                acc[m][n] = __builtin_amdgcn_mfma_f32_16x16x32_f16(af[m], bf[n], acc[m][n], 0, 0, 0);
    }

#pragma unroll
    for (int m = 0; m < 4; ++m) {
        int rb = row0 + m * 16 + k8 * 4;
        float s[4];
#pragma unroll
        for (int r = 0; r < 4; ++r) s[r] = (rb + r < nRows) ? dinv[rb + r] : 0.f;
#pragma unroll
        for (int n = 0; n < NF; ++n) {
            int col = wave * (BN / 4) + n * 16 + fr;
#pragma unroll
            for (int r = 0; r < 4; ++r) {
                int row = rb + r;
                if (row < nRows)
                    HS[(size_t)row * BN + col] = (_Float16)(acc[m][n][r] * s[r]);
            }
        }
    }
}

// ---------------- aggregation (128-channel slice) ----------------
// OUT[v][co] = relu?(dinv[v]*(HS[v][co] + sum_{u->v} HS[u][co]) + b[co])
// 2 nodes/wave; 32 lanes x 8B cover a 128-ch f16 slice (256B granule).
// HS/bias/OUT already offset to the slice by the caller.

template <bool RELU, typename OutT>
__global__ __launch_bounds__(256) void agg_slice_kernel(const _Float16* __restrict__ HS, int ldh,
                                                        const int* __restrict__ rowptr,
                                                        const int* __restrict__ csr,
                                                        const float* __restrict__ dinv,
                                                        const float* __restrict__ bias,
                                                        OutT* __restrict__ OUT, int ldo, int N) {
    int wid = (blockIdx.x << 2) + (threadIdx.x >> 6);
    int lane = threadIdx.x & 63;
    int v = (wid << 1) + (lane >> 5);
    if (v >= N) return;
    int co = (lane & 31) << 2;  // f16 elems; 8B per lane
    const _Float16* base = HS + co;

    f32x4 acc = __builtin_convertvector(*(const half4v*)(base + (size_t)v * ldh), f32x4);
    f32x4 acc2 = {};
    int j = rowptr[v], end = rowptr[v + 1];
    for (; j + 2 <= end; j += 2) {
        int u0 = csr[j], u1 = csr[j + 1];
        acc  += __builtin_convertvector(*(const half4v*)(base + (size_t)u0 * ldh), f32x4);
        acc2 += __builtin_convertvector(*(const half4v*)(base + (size_t)u1 * ldh), f32x4);
    }
    if (j < end)
        acc += __builtin_convertvector(*(const half4v*)(base + (size_t)csr[j] * ldh), f32x4);
    acc += acc2;

    float s = dinv[v];
    f32x4 bb = *(const f32x4*)(bias + co);
    f32x4 o = acc * s + bb;
    if constexpr (RELU) {
        o.x = fmaxf(o.x, 0.f); o.y = fmaxf(o.y, 0.f);
        o.z = fmaxf(o.z, 0.f); o.w = fmaxf(o.w, 0.f);
    }
    if constexpr (sizeof(OutT) == 2) {
        *(half4v*)((_Float16*)OUT + (size_t)v * ldo + co) = __builtin_convertvector(o, half4v);
    } else {
        *(f32x4*)((float*)OUT + (size_t)v * ldo + co) = o;
    }
}

// ---------------- pooling ----------------

__global__ __launch_bounds__(64) void batch_count_kernel(const int* __restrict__ batch, int N,
                                                         int* __restrict__ gcnt) {
    int g = threadIdx.x;
    if (g >= NUM_GRAPHS) return;
    auto lb = [&](int key) {
        int lo = 0, hi = N;
        while (lo < hi) { int mid = (lo + hi) >> 1; if (batch[mid] < key) lo = mid + 1; else hi = mid; }
        return lo;
    };
    gcnt[g] = lb(g + 1) - lb(g);
}

__global__ __launch_bounds__(128) void pool_kernel(const float* __restrict__ H,
                                                   const int* __restrict__ batch,
                                                   float* __restrict__ gsum, int N) {
    const int NODES_PER_BLOCK = 256;
    int c = threadIdx.x;
    int start = blockIdx.x * NODES_PER_BLOCK;
    if (start >= N) return;
    int end = min(start + NODES_PER_BLOCK, N);
    float acc = 0.f;
    int cur = batch[start];
    for (int i = start; i < end; ++i) {
        int b = batch[i];
        if (b != cur) {
            atomicAdd(&gsum[cur * OUT_C + c], acc);
            acc = 0.f;
            cur = b;
        }
        acc += H[(size_t)i * OUT_C + c];
    }
    atomicAdd(&gsum[cur * OUT_C + c], acc);
}

__global__ __launch_bounds__(256) void finalize_kernel(const float* __restrict__ gsum,
                                                       const int* __restrict__ gcnt,
                                                       float* __restrict__ out) {
    int idx = blockIdx.x * 256 + threadIdx.x;
    if (idx < NUM_GRAPHS * OUT_C) {
        int g = idx >> 7;
        out[idx] = gsum[idx] / fmaxf((float)gcnt[g], 1.f);
    }
}

// ---------------- launch ----------------

extern "C" void kernel_launch(void* const* d_in, const int* in_sizes, int n_in,
                              void* d_out, int out_size, void* d_ws, size_t ws_size,
                              hipStream_t stream) {
    const float* x  = (const float*)d_in[0];
    const int* edge = (const int*)d_in[1];
    const int* batch = (const int*)d_in[2];
    const float* W1 = (const float*)d_in[3];
    const float* b1 = (const float*)d_in[4];
    const float* W2 = (const float*)d_in[5];
    const float* b2 = (const float*)d_in[6];
    const float* W3 = (const float*)d_in[7];
    const float* b3 = (const float*)d_in[8];

    const int N = in_sizes[0] / IN_C;
    const int E = in_sizes[1] / 2;
    const int* src = edge;
    const int* dst = edge + E;

    char* ws = (char*)d_ws;
    size_t off = 0;
    auto alloc = [&](size_t bytes) -> void* {
        void* p = ws + off;
        off += (bytes + 255) & ~(size_t)255;
        return p;
    };
    _Float16* hA   = (_Float16*)alloc((size_t)N * HID_C * sizeof(_Float16));
    _Float16* hS   = (_Float16*)alloc((size_t)N * HID_C * sizeof(_Float16));
    float*    h3   = (float*)alloc((size_t)N * OUT_C * sizeof(float));
    _Float16* wt1  = (_Float16*)alloc((size_t)IN_C * HID_C * sizeof(_Float16));
    _Float16* wt2  = (_Float16*)alloc((size_t)HID_C * HID_C * sizeof(_Float16));
    _Float16* wt3  = (_Float16*)alloc((size_t)HID_C * OUT_C * sizeof(_Float16));
    float* dinv    = (float*)alloc((size_t)N * sizeof(float));
    int*   cnt     = (int*)alloc((size_t)N * sizeof(int));
    int*   rowptr  = (int*)alloc((size_t)(N + 1) * sizeof(int));
    int*   fill    = (int*)alloc((size_t)N * sizeof(int));
    int*   csr     = (int*)alloc((size_t)E * sizeof(int));
    float* gsum    = (float*)alloc((size_t)NUM_GRAPHS * OUT_C * sizeof(float));
    int*   gcnt    = (int*)alloc((size_t)NUM_GRAPHS * sizeof(int));

    hipMemsetAsync(cnt, 0, (size_t)N * sizeof(int), stream);
    hipMemsetAsync(fill, 0, (size_t)N * sizeof(int), stream);
    hipMemsetAsync(gsum, 0, (size_t)NUM_GRAPHS * OUT_C * sizeof(float), stream);

    int eb = (E + 255) / 256;
    int nb = (N + 255) / 256;
    int mt = (N + 63) / 64;
    int ab = (((N + 1) / 2) + 3) / 4;  // 2 nodes/wave, 4 waves/block

    count_deg_kernel<<<eb, 256, 0, stream>>>(dst, E, cnt);
    dinv_kernel<<<nb, 256, 0, stream>>>(cnt, dinv, N);
    scan_kernel<<<1, 1024, 0, stream>>>(cnt, rowptr, N);
    scatter_kernel<<<eb, 256, 0, stream>>>(src, dst, E, rowptr, fill, csr);

    wt_f16_kernel<<<(IN_C * HID_C + 255) / 256, 256, 0, stream>>>(W1, wt1, IN_C, HID_C);
    wt_f16_kernel<<<(HID_C * HID_C + 255) / 256, 256, 0, stream>>>(W2, wt2, HID_C, HID_C);
    wt_f16_kernel<<<(HID_C * OUT_C + 255) / 256, 256, 0, stream>>>(W3, wt3, HID_C, OUT_C);

    // layer 1 (f32 input, conversion fused into staging)
    gemm_f16_kernel<256, float><<<mt, 256, 0, stream>>>(x, wt1, dinv, hS, N);
    agg_slice_kernel<true, _Float16><<<ab, 256, 0, stream>>>(hS, 256, rowptr, csr, dinv, b1, hA, 256, N);
    agg_slice_kernel<true, _Float16><<<ab, 256, 0, stream>>>(hS + 128, 256, rowptr, csr, dinv, b1 + 128, hA + 128, 256, N);
    // layer 2
    gemm_f16_kernel<256, _Float16><<<mt, 256, 0, stream>>>(hA, wt2, dinv, hS, N);
    agg_slice_kernel<true, _Float16><<<ab, 256, 0, stream>>>(hS, 256, rowptr, csr, dinv, b2, hA, 256, N);
    agg_slice_kernel<true, _Float16><<<ab, 256, 0, stream>>>(hS + 128, 256, rowptr, csr, dinv, b2 + 128, hA + 128, 256, N);
    // layer 3 (single 128-ch slice, f32 out, no relu)
    gemm_f16_kernel<128, _Float16><<<mt, 256, 0, stream>>>(hA, wt3, dinv, hS, N);
    agg_slice_kernel<false, float><<<ab, 256, 0, stream>>>(hS, 128, rowptr, csr, dinv, b3, h3, 128, N);

    // mean pool
    batch_count_kernel<<<1, 64, 0, stream>>>(batch, N, gcnt);
    pool_kernel<<<(N + 255) / 256, 128, 0, stream>>>(h3, batch, gsum, N);
    finalize_kernel<<<(NUM_GRAPHS * OUT_C + 255) / 256, 256, 0, stream>>>(gsum, gcnt, (float*)d_out);
}

// Round 6
// 1097.072 us; speedup vs baseline: 1.1815x; 1.1815x over previous
//
#include <hip/hip_runtime.h>

#define IN_C 256
#define HID_C 256
#define OUT_C 128
#define NUM_GRAPHS 64

typedef _Float16 half4v __attribute__((ext_vector_type(4)));
typedef _Float16 half8v __attribute__((ext_vector_type(8)));
typedef float f32x4 __attribute__((ext_vector_type(4)));
typedef float f32x8 __attribute__((ext_vector_type(8)));

// ---------------- degree / CSR build ----------------

__global__ __launch_bounds__(256) void count_deg_kernel(const int* __restrict__ dst, int E,
                                                        int* __restrict__ cnt) {
    int e = blockIdx.x * 256 + threadIdx.x;
    if (e < E) atomicAdd(&cnt[dst[e]], 1);
}

__global__ __launch_bounds__(256) void dinv_kernel(const int* __restrict__ cnt,
                                                   float* __restrict__ dinv, int N) {
    int i = blockIdx.x * 256 + threadIdx.x;
    if (i < N) dinv[i] = rsqrtf((float)(cnt[i] + 1));  // +1 self loop
}

// ---- device-wide exclusive scan of cnt -> rowptr (3 kernels) ----

__global__ __launch_bounds__(256) void scan_bsum_kernel(const int* __restrict__ cnt, int N,
                                                        int* __restrict__ bsum) {
    __shared__ int s[256];
    int tid = threadIdx.x;
    int i = blockIdx.x * 256 + tid;
    int v = (i < N) ? cnt[i] : 0;
    s[tid] = v;
    __syncthreads();
    for (int off = 128; off > 0; off >>= 1) {
        if (tid < off) s[tid] += s[tid + off];
        __syncthreads();
    }
    if (tid == 0) bsum[blockIdx.x] = s[0];
}

// single block, 512 threads: exclusive offsets of nb block sums (nb <= 512)
__global__ __launch_bounds__(512) void scan_boff_kernel(const int* __restrict__ bsum, int nb,
                                                        int* __restrict__ boff) {
    __shared__ int s[512];
    int tid = threadIdx.x;
    int v = (tid < nb) ? bsum[tid] : 0;
    s[tid] = v;
    __syncthreads();
    for (int off = 1; off < 512; off <<= 1) {
        int t = (tid >= off) ? s[tid - off] : 0;
        __syncthreads();
        s[tid] += t;
        __syncthreads();
    }
    if (tid < nb) boff[tid] = s[tid] - v;  // exclusive
}

__global__ __launch_bounds__(256) void scan_write_kernel(const int* __restrict__ cnt, int N,
                                                         const int* __restrict__ boff,
                                                         int* __restrict__ rowptr) {
    __shared__ int s[256];
    int tid = threadIdx.x;
    int i = blockIdx.x * 256 + tid;
    int v = (i < N) ? cnt[i] : 0;
    s[tid] = v;
    __syncthreads();
    for (int off = 1; off < 256; off <<= 1) {
        int t = (tid >= off) ? s[tid - off] : 0;
        __syncthreads();
        s[tid] += t;
        __syncthreads();
    }
    int incl = s[tid];
    int bo = boff[blockIdx.x];
    if (i < N) rowptr[i] = bo + incl - v;
    if (i == N - 1) rowptr[N] = bo + incl;
}

__global__ __launch_bounds__(256) void scatter_kernel(const int* __restrict__ src,
                                                      const int* __restrict__ dst, int E,
                                                      const int* __restrict__ rowptr,
                                                      int* __restrict__ fill,
                                                      int* __restrict__ csr) {
    int e = blockIdx.x * 256 + threadIdx.x;
    if (e < E) {
        int d = dst[e];
        int pos = rowptr[d] + atomicAdd(&fill[d], 1);
        csr[pos] = src[e];
    }
}

// ---------------- dtype prep ----------------

// W [K][C] f32  ->  Wt [C][K] f16
__global__ __launch_bounds__(256) void wt_f16_kernel(const float* __restrict__ W,
                                                     _Float16* __restrict__ Wt, int K, int C) {
    int idx = blockIdx.x * 256 + threadIdx.x;
    if (idx < K * C) {
        int k = idx / C, c = idx - k * C;
        Wt[c * K + k] = (_Float16)W[idx];
    }
}

// ---------------- MFMA f16 GEMM with fused dinv row-scale ----------------

template <int BN, typename InT>
__global__ __launch_bounds__(256) void gemm_f16_kernel(const InT* __restrict__ A,
                                                       const _Float16* __restrict__ Bt,
                                                       const float* __restrict__ dinv,
                                                       _Float16* __restrict__ HS,
                                                       int nRows) {
    constexpr int K = 256;
    constexpr int BK = 32;
    constexpr int LDR = 40;
    constexpr int NF = BN / 64;

    __shared__ __align__(16) _Float16 Al[64 * LDR];
    __shared__ __align__(16) _Float16 Bl[BN * LDR];

    const int tid = threadIdx.x;
    const int wave = tid >> 6;
    const int lane = tid & 63;
    const int row0 = blockIdx.x << 6;

    const int ar = tid >> 2;
    const int ac = (tid & 3) << 3;
    const int arow = min(row0 + ar, nRows - 1);

    const int fr = lane & 15;
    const int k8 = lane >> 4;

    f32x4 acc[4][NF] = {};

    for (int k0 = 0; k0 < K; k0 += BK) {
        half8v av;
        if constexpr (sizeof(InT) == 2) {
            av = *(const half8v*)((const _Float16*)A + (size_t)arow * K + k0 + ac);
        } else {
            const float* ap = (const float*)A + (size_t)arow * K + k0 + ac;
            f32x4 lo = *(const f32x4*)(ap);
            f32x4 hi = *(const f32x4*)(ap + 4);
            half4v l = __builtin_convertvector(lo, half4v);
            half4v h = __builtin_convertvector(hi, half4v);
            av = __builtin_shufflevector(l, h, 0, 1, 2, 3, 4, 5, 6, 7);
        }
        half8v bv[NF];
#pragma unroll
        for (int j = 0; j < NF; ++j)
            bv[j] = *(const half8v*)(Bt + (size_t)(ar + 64 * j) * K + k0 + ac);
        __syncthreads();
        *(half8v*)(Al + ar * LDR + ac) = av;
#pragma unroll
        for (int j = 0; j < NF; ++j)
            *(half8v*)(Bl + (ar + 64 * j) * LDR + ac) = bv[j];
        __syncthreads();

        half8v af[4], bf[NF];
#pragma unroll
        for (int m = 0; m < 4; ++m)
            af[m] = *(const half8v*)(Al + (m * 16 + fr) * LDR + k8 * 8);
#pragma unroll
        for (int n = 0; n < NF; ++n)
            bf[n] = *(const half8v*)(Bl + (wave * (BN / 4) + n * 16 + fr) * LDR + k8 * 8);
#pragma unroll
        for (int m = 0; m < 4; ++m)
#pragma unroll
            for (int n = 0; n < NF; ++n)
                acc[m][n] = __builtin_amdgcn_mfma_f32_16x16x32_f16(af[m], bf[n], acc[m][n], 0, 0, 0);
    }

#pragma unroll
    for (int m = 0; m < 4; ++m) {
        int rb = row0 + m * 16 + k8 * 4;
        float s[4];
#pragma unroll
        for (int r = 0; r < 4; ++r) s[r] = (rb + r < nRows) ? dinv[rb + r] : 0.f;
#pragma unroll
        for (int n = 0; n < NF; ++n) {
            int col = wave * (BN / 4) + n * 16 + fr;
#pragma unroll
            for (int r = 0; r < 4; ++r) {
                int row = rb + r;
                if (row < nRows)
                    HS[(size_t)row * BN + col] = (_Float16)(acc[m][n][r] * s[r]);
            }
        }
    }
}

// ---------------- aggregation ----------------
// OUT[v] = relu(dinv[v]*(HS[v] + sum_{u->v} HS[u]) + b)
// C=256: 2 nodes/wave, 32 lanes x 16B per row.

__global__ __launch_bounds__(256) void agg256_f16(const _Float16* __restrict__ HS,
                                                  const int* __restrict__ rowptr,
                                                  const int* __restrict__ csr,
                                                  const float* __restrict__ dinv,
                                                  const float* __restrict__ bias,
                                                  _Float16* __restrict__ OUT, int N) {
    int wid = (blockIdx.x << 2) + (threadIdx.x >> 6);
    int lane = threadIdx.x & 63;
    int v = (wid << 1) + (lane >> 5);
    if (v >= N) return;
    int co = (lane & 31) << 3;  // f16 index; 16B per lane
    const _Float16* base = HS + co;

    f32x8 acc = __builtin_convertvector(*(const half8v*)(base + (size_t)v * 256), f32x8);
    f32x8 acc2 = {};
    int j = rowptr[v], end = rowptr[v + 1];
    for (; j + 2 <= end; j += 2) {
        int u0 = csr[j], u1 = csr[j + 1];
        half8v a = *(const half8v*)(base + (size_t)u0 * 256);
        half8v b = *(const half8v*)(base + (size_t)u1 * 256);
        acc  += __builtin_convertvector(a, f32x8);
        acc2 += __builtin_convertvector(b, f32x8);
    }
    if (j < end)
        acc += __builtin_convertvector(*(const half8v*)(base + (size_t)csr[j] * 256), f32x8);
    acc += acc2;

    float s = dinv[v];
    f32x4 b0 = *(const f32x4*)(bias + co);
    f32x4 b1 = *(const f32x4*)(bias + co + 4);
    f32x8 bb;
    bb.s0 = b0.x; bb.s1 = b0.y; bb.s2 = b0.z; bb.s3 = b0.w;
    bb.s4 = b1.x; bb.s5 = b1.y; bb.s6 = b1.z; bb.s7 = b1.w;
    f32x8 o = acc * s + bb;
#pragma unroll
    for (int t = 0; t < 8; ++t) o[t] = fmaxf(o[t], 0.f);
    *(half8v*)(OUT + (size_t)v * 256 + co) = __builtin_convertvector(o, half8v);
}

// C=128: 4 nodes/wave, 16 lanes x 16B per row; f32 output, no relu.

__global__ __launch_bounds__(256) void agg128_f16(const _Float16* __restrict__ HS,
                                                  const int* __restrict__ rowptr,
                                                  const int* __restrict__ csr,
                                                  const float* __restrict__ dinv,
                                                  const float* __restrict__ bias,
                                                  float* __restrict__ OUT, int N) {
    int wid = (blockIdx.x << 2) + (threadIdx.x >> 6);
    int lane = threadIdx.x & 63;
    int v = (wid << 2) + (lane >> 4);
    if (v >= N) return;
    int co = (lane & 15) << 3;  // f16 index; 16B per lane
    const _Float16* base = HS + co;

    f32x8 acc = __builtin_convertvector(*(const half8v*)(base + (size_t)v * 128), f32x8);
    f32x8 acc2 = {};
    int j = rowptr[v], end = rowptr[v + 1];
    for (; j + 2 <= end; j += 2) {
        int u0 = csr[j], u1 = csr[j + 1];
        half8v a = *(const half8v*)(base + (size_t)u0 * 128);
        half8v b = *(const half8v*)(base + (size_t)u1 * 128);
        acc  += __builtin_convertvector(a, f32x8);
        acc2 += __builtin_convertvector(b, f32x8);
    }
    if (j < end)
        acc += __builtin_convertvector(*(const half8v*)(base + (size_t)csr[j] * 128), f32x8);
    acc += acc2;

    float s = dinv[v];
    f32x4 b0 = *(const f32x4*)(bias + co);
    f32x4 b1 = *(const f32x4*)(bias + co + 4);
    float* op = OUT + (size_t)v * 128 + co;
    f32x4 lo, hi;
    lo.x = acc.s0 * s + b0.x; lo.y = acc.s1 * s + b0.y;
    lo.z = acc.s2 * s + b0.z; lo.w = acc.s3 * s + b0.w;
    hi.x = acc.s4 * s + b1.x; hi.y = acc.s5 * s + b1.y;
    hi.z = acc.s6 * s + b1.z; hi.w = acc.s7 * s + b1.w;
    *(f32x4*)(op) = lo;
    *(f32x4*)(op + 4) = hi;
}

// ---------------- pooling ----------------

__global__ __launch_bounds__(64) void batch_count_kernel(const int* __restrict__ batch, int N,
                                                         int* __restrict__ gcnt) {
    int g = threadIdx.x;
    if (g >= NUM_GRAPHS) return;
    auto lb = [&](int key) {
        int lo = 0, hi = N;
        while (lo < hi) { int mid = (lo + hi) >> 1; if (batch[mid] < key) lo = mid + 1; else hi = mid; }
        return lo;
    };
    gcnt[g] = lb(g + 1) - lb(g);
}

__global__ __launch_bounds__(128) void pool_kernel(const float* __restrict__ H,
                                                   const int* __restrict__ batch,
                                                   float* __restrict__ gsum, int N) {
    const int NODES_PER_BLOCK = 256;
    int c = threadIdx.x;
    int start = blockIdx.x * NODES_PER_BLOCK;
    if (start >= N) return;
    int end = min(start + NODES_PER_BLOCK, N);
    float acc = 0.f;
    int cur = batch[start];
    for (int i = start; i < end; ++i) {
        int b = batch[i];
        if (b != cur) {
            atomicAdd(&gsum[cur * OUT_C + c], acc);
            acc = 0.f;
            cur = b;
        }
        acc += H[(size_t)i * OUT_C + c];
    }
    atomicAdd(&gsum[cur * OUT_C + c], acc);
}

__global__ __launch_bounds__(256) void finalize_kernel(const float* __restrict__ gsum,
                                                       const int* __restrict__ gcnt,
                                                       float* __restrict__ out) {
    int idx = blockIdx.x * 256 + threadIdx.x;
    if (idx < NUM_GRAPHS * OUT_C) {
        int g = idx >> 7;
        out[idx] = gsum[idx] / fmaxf((float)gcnt[g], 1.f);
    }
}

// ---------------- launch ----------------

extern "C" void kernel_launch(void* const* d_in, const int* in_sizes, int n_in,
                              void* d_out, int out_size, void* d_ws, size_t ws_size,
                              hipStream_t stream) {
    const float* x  = (const float*)d_in[0];
    const int* edge = (const int*)d_in[1];
    const int* batch = (const int*)d_in[2];
    const float* W1 = (const float*)d_in[3];
    const float* b1 = (const float*)d_in[4];
    const float* W2 = (const float*)d_in[5];
    const float* b2 = (const float*)d_in[6];
    const float* W3 = (const float*)d_in[7];
    const float* b3 = (const float*)d_in[8];

    const int N = in_sizes[0] / IN_C;
    const int E = in_sizes[1] / 2;
    const int* src = edge;
    const int* dst = edge + E;

    char* ws = (char*)d_ws;
    size_t off = 0;
    auto alloc = [&](size_t bytes) -> void* {
        void* p = ws + off;
        off += (bytes + 255) & ~(size_t)255;
        return p;
    };
    _Float16* hA   = (_Float16*)alloc((size_t)N * HID_C * sizeof(_Float16));
    _Float16* hS   = (_Float16*)alloc((size_t)N * HID_C * sizeof(_Float16));
    float*    h3   = (float*)alloc((size_t)N * OUT_C * sizeof(float));
    _Float16* wt1  = (_Float16*)alloc((size_t)IN_C * HID_C * sizeof(_Float16));
    _Float16* wt2  = (_Float16*)alloc((size_t)HID_C * HID_C * sizeof(_Float16));
    _Float16* wt3  = (_Float16*)alloc((size_t)HID_C * OUT_C * sizeof(_Float16));
    float* dinv    = (float*)alloc((size_t)N * sizeof(float));
    int*   cnt     = (int*)alloc((size_t)N * sizeof(int));
    int*   rowptr  = (int*)alloc((size_t)(N + 1) * sizeof(int));
    int*   fill    = (int*)alloc((size_t)N * sizeof(int));
    int*   csr     = (int*)alloc((size_t)E * sizeof(int));
    int*   bsum    = (int*)alloc((size_t)512 * sizeof(int));
    int*   boff    = (int*)alloc((size_t)512 * sizeof(int));
    float* gsum    = (float*)alloc((size_t)NUM_GRAPHS * OUT_C * sizeof(float));
    int*   gcnt    = (int*)alloc((size_t)NUM_GRAPHS * sizeof(int));

    hipMemsetAsync(cnt, 0, (size_t)N * sizeof(int), stream);
    hipMemsetAsync(fill, 0, (size_t)N * sizeof(int), stream);
    hipMemsetAsync(gsum, 0, (size_t)NUM_GRAPHS * OUT_C * sizeof(float), stream);

    int eb = (E + 255) / 256;
    int nb = (N + 255) / 256;
    int mt = (N + 63) / 64;
    int ab256 = (((N + 1) / 2) + 3) / 4;  // 2 nodes/wave, 4 waves/block
    int ab128 = (((N + 3) / 4) + 3) / 4;  // 4 nodes/wave, 4 waves/block

    count_deg_kernel<<<eb, 256, 0, stream>>>(dst, E, cnt);
    dinv_kernel<<<nb, 256, 0, stream>>>(cnt, dinv, N);
    scan_bsum_kernel<<<nb, 256, 0, stream>>>(cnt, N, bsum);
    scan_boff_kernel<<<1, 512, 0, stream>>>(bsum, nb, boff);
    scan_write_kernel<<<nb, 256, 0, stream>>>(cnt, N, boff, rowptr);
    scatter_kernel<<<eb, 256, 0, stream>>>(src, dst, E, rowptr, fill, csr);

    wt_f16_kernel<<<(IN_C * HID_C + 255) / 256, 256, 0, stream>>>(W1, wt1, IN_C, HID_C);
    wt_f16_kernel<<<(HID_C * HID_C + 255) / 256, 256, 0, stream>>>(W2, wt2, HID_C, HID_C);
    wt_f16_kernel<<<(HID_C * OUT_C + 255) / 256, 256, 0, stream>>>(W3, wt3, HID_C, OUT_C);

    // layer 1 (f32 input, conversion fused into staging)
    gemm_f16_kernel<256, float><<<mt, 256, 0, stream>>>(x, wt1, dinv, hS, N);
    agg256_f16<<<ab256, 256, 0, stream>>>(hS, rowptr, csr, dinv, b1, hA, N);
    // layer 2
    gemm_f16_kernel<256, _Float16><<<mt, 256, 0, stream>>>(hA, wt2, dinv, hS, N);
    agg256_f16<<<ab256, 256, 0, stream>>>(hS, rowptr, csr, dinv, b2, hA, N);
    // layer 3 (C=128, f32 out)
    gemm_f16_kernel<128, _Float16><<<mt, 256, 0, stream>>>(hA, wt3, dinv, hS, N);
    agg128_f16<<<ab128, 256, 0, stream>>>(hS, rowptr, csr, dinv, b3, h3, N);

    // mean pool
    batch_count_kernel<<<1, 64, 0, stream>>>(batch, N, gcnt);
    pool_kernel<<<(N + 255) / 256, 128, 0, stream>>>(h3, batch, gsum, N);
    finalize_kernel<<<(NUM_GRAPHS * OUT_C + 255) / 256, 256, 0, stream>>>(gsum, gcnt, (float*)d_out);
}